// Round 1
// baseline (220.885 us; speedup 1.0000x reference)
//
#include <hip/hip_runtime.h>

// Centroid update via counting sort + streaming gather.
//   sums[c,:] = sum_{i: y[i]==c} embed[i,:]
//   out[c,:]  = 0.3 * sums[c,:]/count[c] + 0.7 * centroid[c,:]
//
// Previous version (206 µs) had every block re-scan all of y with 3 barriers
// per 1024-label chunk — latency/serialization-bound at ~10% of HBM roofline.
// New structure: sort row indices by class first (4 tiny kernels, ~130 KB of
// traffic total), then a gather kernel where each block streams ONLY its own
// class's rows: 128 MiB of perfectly coalesced 4 KB row reads, read exactly
// once device-wide. Roofline ≈ 140 MB / 6.3 TB/s ≈ 22 µs + small-kernel tax.

#define BATCH       32768
#define EMBED_DIM   1024
#define NUM_CLASSES 1000
#define FACTOR      0.3f

// ---------------- workspace layout (ints) ----------------
// ws[0    .. 1023]  : cnt / cursor   (histogram counts, then scatter cursor)
// ws[1024 .. 2047]  : offs           (exclusive offsets, offs[1000] = BATCH)
// ws[2048 .. 34815] : rowlist        (row indices sorted by class)

__global__ __launch_bounds__(1024) void zero_kernel(int* __restrict__ cnt)
{
    cnt[threadIdx.x] = 0;
}

__global__ __launch_bounds__(256) void hist_kernel(const int* __restrict__ y,
                                                   int* __restrict__ cnt)
{
    const int i = blockIdx.x * 256 + threadIdx.x;
    atomicAdd(&cnt[y[i]], 1);
}

// Single-block Hillis-Steele scan over 1024 slots (1000 live).
// Writes exclusive offsets to offs[] AND back into cnt[] (scatter cursor),
// plus offs[NUM_CLASSES] = total.
__global__ __launch_bounds__(1024) void scan_kernel(int* __restrict__ cnt,
                                                    int* __restrict__ offs)
{
    __shared__ int s[1024];
    const int t = threadIdx.x;
    const int v = (t < NUM_CLASSES) ? cnt[t] : 0;
    s[t] = v;
    __syncthreads();
    #pragma unroll
    for (int d = 1; d < 1024; d <<= 1) {
        const int x = (t >= d) ? s[t - d] : 0;
        __syncthreads();
        s[t] += x;
        __syncthreads();
    }
    const int excl = s[t] - v;            // exclusive prefix
    if (t < NUM_CLASSES) { offs[t] = excl; cnt[t] = excl; }
    if (t == 1023) offs[NUM_CLASSES] = s[1023];   // total == BATCH
}

__global__ __launch_bounds__(256) void scatter_kernel(const int* __restrict__ y,
                                                      int* __restrict__ cursor,
                                                      int* __restrict__ rowlist)
{
    const int i = blockIdx.x * 256 + threadIdx.x;
    const int c = y[i];
    const int pos = atomicAdd(&cursor[c], 1);
    rowlist[pos] = i;
}

// One block per class. 256 threads x float4 = 1024 dims. Stream the class's
// row list in LDS chunks of 256 indices; inner loop unrolled 4x so four
// independent 1 KB/wave row loads are in flight per wave.
__global__ __launch_bounds__(256) void gather_kernel(
    const float* __restrict__ embed,
    const float* __restrict__ centroid,
    const int*   __restrict__ offs,
    const int*   __restrict__ rowlist,
    float*       __restrict__ out)
{
    const int c   = blockIdx.x;
    const int tid = threadIdx.x;
    const int d0  = tid * 4;

    const int start = offs[c];
    const int m     = offs[c + 1] - start;

    __shared__ int rows[256];

    float4 acc = make_float4(0.f, 0.f, 0.f, 0.f);

    for (int base = 0; base < m; base += 256) {
        const int k = min(256, m - base);
        if (tid < k) rows[tid] = rowlist[start + base + tid];
        __syncthreads();

        int j = 0;
        for (; j + 4 <= k; j += 4) {
            const int r0 = rows[j + 0];
            const int r1 = rows[j + 1];
            const int r2 = rows[j + 2];
            const int r3 = rows[j + 3];
            const float4 v0 = *reinterpret_cast<const float4*>(embed + (size_t)r0 * EMBED_DIM + d0);
            const float4 v1 = *reinterpret_cast<const float4*>(embed + (size_t)r1 * EMBED_DIM + d0);
            const float4 v2 = *reinterpret_cast<const float4*>(embed + (size_t)r2 * EMBED_DIM + d0);
            const float4 v3 = *reinterpret_cast<const float4*>(embed + (size_t)r3 * EMBED_DIM + d0);
            acc.x += v0.x; acc.y += v0.y; acc.z += v0.z; acc.w += v0.w;
            acc.x += v1.x; acc.y += v1.y; acc.z += v1.z; acc.w += v1.w;
            acc.x += v2.x; acc.y += v2.y; acc.z += v2.z; acc.w += v2.w;
            acc.x += v3.x; acc.y += v3.y; acc.z += v3.z; acc.w += v3.w;
        }
        for (; j < k; ++j) {
            const int r = rows[j];
            const float4 v = *reinterpret_cast<const float4*>(embed + (size_t)r * EMBED_DIM + d0);
            acc.x += v.x; acc.y += v.y; acc.z += v.z; acc.w += v.w;
        }
        __syncthreads();
    }

    // Epilogue: mean, blend, store. m==0 -> 0 * inf = NaN, matching reference.
    const float inv = 1.0f / (float)m;
    const size_t o = (size_t)c * EMBED_DIM + d0;
    const float4 cen = *reinterpret_cast<const float4*>(centroid + o);
    float4 res;
    res.x = FACTOR * (acc.x * inv) + (1.0f - FACTOR) * cen.x;
    res.y = FACTOR * (acc.y * inv) + (1.0f - FACTOR) * cen.y;
    res.z = FACTOR * (acc.z * inv) + (1.0f - FACTOR) * cen.z;
    res.w = FACTOR * (acc.w * inv) + (1.0f - FACTOR) * cen.w;
    *reinterpret_cast<float4*>(out + o) = res;
}

extern "C" void kernel_launch(void* const* d_in, const int* in_sizes, int n_in,
                              void* d_out, int out_size, void* d_ws, size_t ws_size,
                              hipStream_t stream) {
    const float* embed    = (const float*)d_in[0];  // [32768, 1024]
    const int*   y        = (const int*)d_in[1];    // [32768] (int32 in harness)
    const float* centroid = (const float*)d_in[2];  // [1000, 1024]
    float*       out      = (float*)d_out;          // [1000, 1024]

    int* ws      = (int*)d_ws;
    int* cnt     = ws;          // 1024 ints (counts, then cursor)
    int* offs    = ws + 1024;   // 1001 ints
    int* rowlist = ws + 2048;   // 32768 ints

    zero_kernel   <<<1, 1024, 0, stream>>>(cnt);
    hist_kernel   <<<BATCH / 256, 256, 0, stream>>>(y, cnt);
    scan_kernel   <<<1, 1024, 0, stream>>>(cnt, offs);
    scatter_kernel<<<BATCH / 256, 256, 0, stream>>>(y, cnt, rowlist);
    gather_kernel <<<NUM_CLASSES, 256, 0, stream>>>(embed, centroid, offs, rowlist, out);
}